// Round 7
// baseline (137.656 us; speedup 1.0000x reference)
//
#include <hip/hip_runtime.h>
#include <hip/hip_fp16.h>
#include <cstdint>

#define IMG_H 512
#define IMG_W 512
#define ROW_BYTES (IMG_W * 4)
#define NPLANES 48                  // 16 batch * 3 channels
#define PLANE_SZ (IMG_H * IMG_W)
#define N_ELEM (NPLANES * PLANE_SZ) // 12,582,912

#define TILE_W 48
#define TILE_H 32
#define GX 11
#define GY 16
#define NBLOCKS (GX * GY * NPLANES) // 8448
#define NPART (NBLOCKS * 4)         // one fp32 partial per wave: 33792
#define VPITCH 59                   // stored halo cols 0..57 (+1 pad)

#define SSIM_C1 1e-4f
#define SSIM_C2 9e-4f

// Raw buffer load: OOB (row<0 / row>=H via soffset; bad col via huge voffset)
// returns 0.0f in hardware = free 'SAME' zero padding, zero bounds VALU.
typedef int rsrc_t __attribute__((ext_vector_type(4)));
__device__ float
llvm_amdgcn_raw_buffer_load_fp32(rsrc_t srsrc, int voffset, int soffset,
                                 int glc_slc) __asm("llvm.amdgcn.raw.buffer.load.f32");

__device__ inline rsrc_t make_rsrc(const void* p, int bytes) {
    rsrc_t r;
    r.x = (int)(uint32_t)(uintptr_t)p;       // base lo
    r.y = (int)((uintptr_t)p >> 32);         // base hi, stride=0
    r.z = bytes;                             // num_records (bytes)
    r.w = 0x00020000;                        // raw dword SRD word3
    return r;
}

// Separable 11x11 Gaussian over channels (s=x+y, d=x-y, s^2, d^2).
// R7: vertical sums stored in LDS as fp16 pairs (RN! pkrtz/RTZ bias would
// shift the mean past threshold) -> 14.9 KB/block -> 8 blocks/CU = 32 waves
// (R3->R4 showed dur ~ 1/waves; 32 waves should pin dur at the ~30 us VALU
// issue floor). Packed fp32 dropped: v_pk_fma_f32 is rate-neutral on gfx950
// (157.3 TF peak = scalar fma at SIMD32 already).
__global__ __launch_bounds__(256, 8) void ssim_tile_kernel(
    const float* __restrict__ img1, const float* __restrict__ img2,
    float* __restrict__ partials)
{
    // w.x = half2(vs_s, vs_d), w.y = half2(vs_s2, vs_d2).
    // Bank check: write lane=col -> dwords 2*lane+{0,1} -> 4/bank even;
    // read (8 rows x 8 colgroups): rowstride 118, colstride 12 dwords ->
    // exactly 4 dwords/bank. Conflict-free both ways.
    __shared__ uint2 vs[TILE_H][VPITCH];   // 14.9 KB

    // exact gaussian(ws=11, sigma=1.5) weights (normalized, ~1e-8 abs)
    const float gw[11] = {0.00102838f, 0.00759876f, 0.03600077f, 0.10936069f,
                          0.21300553f, 0.26601172f, 0.21300553f, 0.10936069f,
                          0.03600077f, 0.00759876f, 0.00102838f};

    const int tid  = threadIdx.x;
    const int lane = tid & 63;
    const int wv   = tid >> 6;
    const int r0   = wv * 8;                 // this wave's 8 output rows
    const int ox = blockIdx.x * TILE_W;
    const int oy = blockIdx.y * TILE_H;

    const float* p1 = img1 + (size_t)blockIdx.z * PLANE_SZ;
    const float* p2 = img2 + (size_t)blockIdx.z * PLANE_SZ;
    const rsrc_t rr1 = make_rsrc(p1, PLANE_SZ * 4);
    const rsrc_t rr2 = make_rsrc(p2, PLANE_SZ * 4);

    // ---- vertical pass: lane = halo col, input rows oy+r0-5 .. oy+r0+12
    {
        const int srow0 = __builtin_amdgcn_readfirstlane(oy + r0 - 5); // SGPR
        const int gcol = ox + lane - 5;
        const int coff = ((unsigned)gcol < (unsigned)IMG_W) ? (gcol * 4) : 0x48000000;

        float xs[18], ys[18];
        #pragma unroll
        for (int i = 0; i < 18; ++i) {
            const int soff = (srow0 + i) * ROW_BYTES;  // SGPR soffset
            xs[i] = llvm_amdgcn_raw_buffer_load_fp32(rr1, coff, soff, 0);
            ys[i] = llvm_amdgcn_raw_buffer_load_fp32(rr2, coff, soff, 0);
        }

        float as[8], ad[8], as2[8], ad2[8];
        #pragma unroll
        for (int o = 0; o < 8; ++o) { as[o]=0.f; ad[o]=0.f; as2[o]=0.f; ad2[o]=0.f; }
        #pragma unroll
        for (int i = 0; i < 18; ++i) {
            const float s = xs[i] + ys[i], d = xs[i] - ys[i];
            const float s2 = s * s, d2 = d * d;
            #pragma unroll
            for (int o = 0; o < 8; ++o) {
                const int k = i - o;                   // tap index (static)
                if (k >= 0 && k <= 10) {
                    const float w = gw[k];
                    as[o]  = fmaf(w, s,  as[o]);
                    ad[o]  = fmaf(w, d,  ad[o]);
                    as2[o] = fmaf(w, s2, as2[o]);
                    ad2[o] = fmaf(w, d2, ad2[o]);
                }
            }
        }
        if (lane < 58) {                               // only cols horizontal reads
            #pragma unroll
            for (int o = 0; o < 8; ++o) {
                const __half2 hP = __floats2half2_rn(as[o],  ad[o]);   // RN!
                const __half2 hQ = __floats2half2_rn(as2[o], ad2[o]);  // RN!
                vs[r0 + o][lane] = make_uint2(__builtin_bit_cast(unsigned, hP),
                                              __builtin_bit_cast(unsigned, hQ));
            }
        }
    }
    // NO barrier: wave reads back only rows r0..r0+7 it just wrote
    // (compiler-inserted s_waitcnt lgkmcnt orders intra-wave LDS write->read).

    // ---- horizontal pass + SSIM: lane -> row r0+(lane>>3), 6 consecutive cols
    float lsum = 0.f;
    {
        const int r  = r0 + (lane >> 3);
        const int c0 = (lane & 7) * 6;                 // max read col 42+15=57
        float ms[6], md[6], ms2[6], md2[6];
        #pragma unroll
        for (int j = 0; j < 6; ++j) { ms[j]=0.f; md[j]=0.f; ms2[j]=0.f; md2[j]=0.f; }
        #pragma unroll
        for (int t = 0; t < 16; ++t) {
            const uint2 w2 = vs[r][c0 + t];            // one ds_read_b64
            const float2 vP = __half22float2(__builtin_bit_cast(__half2, w2.x));
            const float2 vQ = __half22float2(__builtin_bit_cast(__half2, w2.y));
            #pragma unroll
            for (int j = 0; j < 6; ++j) {
                const int k = t - j;
                if (k >= 0 && k <= 10) {
                    const float w = gw[k];
                    ms[j]  = fmaf(w, vP.x, ms[j]);
                    md[j]  = fmaf(w, vP.y, md[j]);
                    ms2[j] = fmaf(w, vQ.x, ms2[j]);
                    md2[j] = fmaf(w, vQ.y, md2[j]);
                }
            }
        }
        #pragma unroll
        for (int j = 0; j < 6; ++j) {
            if (ox + c0 + j < IMG_W) {                 // clip right-edge tile
                const float mus = ms[j], mud = md[j];
                const float es2 = ms2[j], ed2 = md2[j];
                const float a = mus * mus, b = mud * mud;
                // mu1 = (mus+mud)/2, mu2 = (mus-mud)/2:
                const float num1 = (a - b) * 0.5f + SSIM_C1;               // 2*mu1*mu2 + C1
                const float den1 = (a + b) * 0.5f + SSIM_C1;               // mu1^2+mu2^2 + C1
                const float num2 = (es2 - ed2 - (a - b)) * 0.5f + SSIM_C2; // 2*sigma12 + C2
                const float den2 = (es2 + ed2 - (a + b)) * 0.5f + SSIM_C2; // s1+s2 + C2
                lsum += (num1 * num2) * __builtin_amdgcn_rcpf(den1 * den2);
            }
        }
    }

    // ---- per-wave reduction -> fp32 partial, plain store, no cross-wave sync
    #pragma unroll
    for (int off = 32; off > 0; off >>= 1)
        lsum += __shfl_down(lsum, off, 64);
    if (lane == 0) {
        const int bid = blockIdx.x + GX * (blockIdx.y + GY * blockIdx.z);
        partials[(bid << 2) | wv] = lsum;
    }
}

// 1 block x 1024 threads: 33 independent fp32 loads/thread, f64 accumulate.
__global__ __launch_bounds__(1024) void ssim_finalize_kernel(
    const float* __restrict__ partials, float* __restrict__ out)
{
    __shared__ double wred[16];
    const int tid  = threadIdx.x;
    const int lane = tid & 63;
    const int wv   = tid >> 6;
    double s = 0.0;
    #pragma unroll
    for (int i = 0; i < 33; ++i)               // 33*1024 == 33792 exactly
        s += (double)partials[tid + i * 1024];
    #pragma unroll
    for (int off = 32; off > 0; off >>= 1)
        s += __shfl_down(s, off, 64);
    if (lane == 0) wred[wv] = s;
    __syncthreads();
    if (wv == 0) {
        double v = (lane < 16) ? wred[lane] : 0.0;
        v += __shfl_down(v, 8, 64);
        v += __shfl_down(v, 4, 64);
        v += __shfl_down(v, 2, 64);
        v += __shfl_down(v, 1, 64);
        if (lane == 0) out[0] = (float)(v / (double)N_ELEM);
    }
}

extern "C" void kernel_launch(void* const* d_in, const int* in_sizes, int n_in,
                              void* d_out, int out_size, void* d_ws, size_t ws_size,
                              hipStream_t stream)
{
    const float* img1 = (const float*)d_in[0];
    const float* img2 = (const float*)d_in[1];
    float* partials   = (float*)d_ws;           // 33792 * 4B = 135 KB scratch
    float* out        = (float*)d_out;

    dim3 grid(GX, GY, NPLANES);
    ssim_tile_kernel<<<grid, dim3(256), 0, stream>>>(img1, img2, partials);
    ssim_finalize_kernel<<<1, dim3(1024), 0, stream>>>(partials, out);
}

// Round 9
// 137.415 us; speedup vs baseline: 1.0018x; 1.0018x over previous
//
#include <hip/hip_runtime.h>
#include <cstdint>

#define IMG_H 512
#define IMG_W 512
#define ROW_BYTES (IMG_W * 4)
#define NPLANES 48                  // 16 batch * 3 channels
#define PLANE_SZ (IMG_H * IMG_W)
#define N_ELEM (NPLANES * PLANE_SZ) // 12,582,912

#define GXB 8                       // 8 col-tiles of 64
#define GYB 8                       // 8 row-tiles of 64 (4 waves x 16 rows)
#define NBLOCKS (GXB * GYB * NPLANES) // 3072
#define NPART (NBLOCKS * 4)           // 12288 per-wave partials

#define SSIM_C1 1e-4f
#define SSIM_C2 9e-4f

// vsum ring in LDS: per wave, per channel, 16 rows x PITCH f16 (2 slots of 16 cols)
#define PITCH 40                    // f16/row: 32 used + 8 pad (16B-aligned rows)
#define CH_STRIDE (16 * PITCH)      // 640 f16
#define WV_STRIDE (4 * CH_STRIDE)   // 2560 f16 = 5120 B

typedef _Float16 f16x8 __attribute__((ext_vector_type(8)));  // MFMA A/B frag (4 VGPR)
typedef float f32x4 __attribute__((ext_vector_type(4)));     // MFMA C/D frag
typedef int rsrc_t __attribute__((ext_vector_type(4)));

// Raw buffer load: OOB returns 0 => free 'SAME' zero padding (rows via negative/
// huge offsets, cols forced OOB via huge voffset). Centered channels p=x+y-1
// break at pad! -> but pads are only where weight contribution must be zero:
// reference zero-pads x,y, i.e. pads contribute x=y=0 -> p=-1, m=0. We instead
// let OOB return 0 for the *uncentered* sum by loading x,y and centering in
// registers only for in-range ROWS... NO: simpler & exact: conv is linear; we
// convolve p'=x+y-1 treating OOB as p'=0, then the difference vs reference's
// (x=y=0 => p'=-1) is +1*(sum of weights over OOB taps) in mu_s. Reference
// pads with ZEROS for x,y, so reference mu_s includes those taps as 0 = our
// p'=0 plus the +1 shift applied to ALL taps... MISMATCH at borders.
// Resolution used here: load a per-tap validity-free formulation — we center
// with the *indicator*: load v = x+y (OOB->0) and subtract the convolution of
// the indicator function 1_valid. 1_valid conv = ones-conv, which we get for
// free: conv2(1) over valid taps = (colsum)x(rowsum) separable... that costs a
// 5th channel. Cheaper exact trick: only interior pixels (99.2% of image) have
// all taps valid where centering is exact; border pixels (rows/cols <5 or
// >=507) are computed UNCENTERED in a scalar fallback pass? Too complex.
// FINAL CHOICE (implemented): convolve the 5th channel "ones" via the SAME
// MFMA path (indicator u=1 in-range, 0 OOB) packed into spare K capacity is
// not free; instead we simply DON'T center the mu channels (S,D as in R8:
// s=x+y, d=x-y, OOB=0 exact) and center ONLY the squared channels around the
// in-register value: q_p = (s-1)^2, q_m = d^2 computed from the SAME loaded
// s (OOB s=0 -> q_p=1 WRONG at pads)... see below: we keep R8 channels
// s,d,s2,d2 (pad-exact) and fix ONLY the weight-scale bias with rs=1/S^2,
// which the R8 error analysis showed is the entire 9.8e-4.
__device__ float
llvm_amdgcn_raw_buffer_load_fp32(rsrc_t srsrc, int voffset, int soffset,
                                 int glc_slc) __asm("llvm.amdgcn.raw.buffer.load.f32");

__device__ inline rsrc_t make_rsrc(const void* p, int bytes) {
    rsrc_t r;
    r.x = (int)(uint32_t)(uintptr_t)p;
    r.y = (int)((uintptr_t)p >> 32);
    r.z = bytes;                     // num_records
    r.w = 0x00020000;                // raw dword SRD word3
    return r;
}

// MFMA-based SSIM: vertical conv = MFMA(W_toeplitz, In), horizontal conv =
// MFMA(Vsum, G_toeplitz), f16 inputs / f32 accum. Wave = 16 rows x 64 cols.
// R9 fix: rescale all conv outputs by rs = 1/S^2 (S = sum of f16 weights).
// R8's absmax 9.77e-4 == predicted 0.0053*(S-1)/C2 -> weight-sum bias was
// the entire error; everything else (layouts, padding) verified correct.
__global__ __launch_bounds__(256, 4) void ssim_tile_kernel(
    const float* __restrict__ img1, const float* __restrict__ img2,
    float* __restrict__ partials)
{
    __shared__ __align__(16) _Float16 wtab[512];          // gw[k-m] 64 lanes x 8
    __shared__ __align__(16) _Float16 vsum[4 * WV_STRIDE];// 20.5 KB ring

    const int tid  = threadIdx.x;
    const int lane = tid & 63;
    const int wv   = tid >> 6;
    const int n    = lane & 15;      // MFMA m/n index
    const int q    = lane >> 4;      // quad

    // exact gaussian(ws=11, sigma=1.5) weights (normalized, ~1e-8 abs)
    const float gwc[11] = {0.00102838f, 0.00759876f, 0.03600077f, 0.10936069f,
                           0.21300553f, 0.26601172f, 0.21300553f, 0.10936069f,
                           0.03600077f, 0.00759876f, 0.00102838f};

    // ---- one-time Toeplitz table: wtab[l][j] = gw[k-m], k=(l>>4)*8+j, m=l&15
    for (int idx = tid; idx < 512; idx += 256) {
        const int l = idx >> 3, j = idx & 7;
        const int d = ((l >> 4) * 8 + j) - (l & 15);
        wtab[idx] = (_Float16)((d >= 0 && d <= 10) ? gwc[d] : 0.0f);
    }
    __syncthreads();
    const f16x8 wfrag = *(const f16x8*)(wtab + lane * 8); // A for V-pass, B for H-pass

    // rs = 1/S^2: S = effective f16 weight sum (deterministic RN rounding).
    // Removes the S^2-vs-S^4 scale mismatch between E[s^2] and mu^2 that the
    // C2-cancellation amplifies ~1100x (R8 post-mortem).
    float S = 0.f;
    #pragma unroll
    for (int k = 0; k < 11; ++k) S += (float)(_Float16)gwc[k];
    const float rs = 1.0f / (S * S);

    const int C0 = blockIdx.x * 64;
    const int R0 = blockIdx.y * 64 + wv * 16;
    const float* p1 = img1 + (size_t)blockIdx.z * PLANE_SZ;
    const float* p2 = img2 + (size_t)blockIdx.z * PLANE_SZ;
    const rsrc_t rr1 = make_rsrc(p1, PLANE_SZ * 4);
    const rsrc_t rr2 = make_rsrc(p2, PLANE_SZ * 4);

    const int rowterm = (R0 - 5 + q * 8) * ROW_BYTES;  // per-lane k-row base (neg -> OOB)
    _Float16* vbase = vsum + wv * WV_STRIDE;           // this wave's private ring
    float lsum = 0.f;

    // ---- vertical MFMA for 16-col patch t (ring slot t&1) ----
    auto do_V = [&](int t) {
        const int col  = C0 - 5 + 16 * t + n;
        const int coff = ((unsigned)col < (unsigned)IMG_W) ? (col * 4) : 0x48000000;
        const int vb   = coff + rowterm;
        float xs[8], ys[8];
        #pragma unroll
        for (int j = 0; j < 8; ++j) {
            xs[j] = llvm_amdgcn_raw_buffer_load_fp32(rr1, vb + j * ROW_BYTES, 0, 0);
            ys[j] = llvm_amdgcn_raw_buffer_load_fp32(rr2, vb + j * ROW_BYTES, 0, 0);
        }
        f16x8 fS, fD, fS2, fD2;
        #pragma unroll
        for (int j = 0; j < 8; ++j) {
            const float s = xs[j] + ys[j], d = xs[j] - ys[j];
            fS[j]  = (_Float16)s;         // RN (default v_cvt_f16_f32 mode)
            fD[j]  = (_Float16)d;
            fS2[j] = (_Float16)(s * s);
            fD2[j] = (_Float16)(d * d);
        }
        const f32x4 z = {0.f, 0.f, 0.f, 0.f};
        const f32x4 cS  = __builtin_amdgcn_mfma_f32_16x16x32_f16(wfrag, fS,  z, 0, 0, 0);
        const f32x4 cD  = __builtin_amdgcn_mfma_f32_16x16x32_f16(wfrag, fD,  z, 0, 0, 0);
        const f32x4 cS2 = __builtin_amdgcn_mfma_f32_16x16x32_f16(wfrag, fS2, z, 0, 0, 0);
        const f32x4 cD2 = __builtin_amdgcn_mfma_f32_16x16x32_f16(wfrag, fD2, z, 0, 0, 0);
        // C-layout: col=n, row=q*4+r -> ring slot t&1
        _Float16* wp = vbase + (q * 4) * PITCH + 16 * (t & 1) + n;
        #pragma unroll
        for (int r = 0; r < 4; ++r) {
            wp[r * PITCH + 0 * CH_STRIDE] = (_Float16)cS[r];
            wp[r * PITCH + 1 * CH_STRIDE] = (_Float16)cD[r];
            wp[r * PITCH + 2 * CH_STRIDE] = (_Float16)cS2[r];
            wp[r * PITCH + 3 * CH_STRIDE] = (_Float16)cD2[r];
        }
    };

    // ---- horizontal MFMA + SSIM epilogue for 16-col out patch u ----
    auto do_H = [&](int u) {
        const int kbase = (16 * u + q * 8) & 31;       // 8 contiguous, 16B aligned
        const _Float16* rp = vbase + n * PITCH + kbase;
        const f16x8 aS  = *(const f16x8*)(rp + 0 * CH_STRIDE);
        const f16x8 aD  = *(const f16x8*)(rp + 1 * CH_STRIDE);
        const f16x8 aS2 = *(const f16x8*)(rp + 2 * CH_STRIDE);
        const f16x8 aD2 = *(const f16x8*)(rp + 3 * CH_STRIDE);
        const f32x4 z = {0.f, 0.f, 0.f, 0.f};
        const f32x4 hS  = __builtin_amdgcn_mfma_f32_16x16x32_f16(aS,  wfrag, z, 0, 0, 0);
        const f32x4 hD  = __builtin_amdgcn_mfma_f32_16x16x32_f16(aD,  wfrag, z, 0, 0, 0);
        const f32x4 hS2 = __builtin_amdgcn_mfma_f32_16x16x32_f16(aS2, wfrag, z, 0, 0, 0);
        const f32x4 hD2 = __builtin_amdgcn_mfma_f32_16x16x32_f16(aD2, wfrag, z, 0, 0, 0);
        #pragma unroll
        for (int r = 0; r < 4; ++r) {      // px: row R0+q*4+r, col C0+16u+n
            const float mus = hS[r]  * rs, mud = hD[r]  * rs;
            const float es2 = hS2[r] * rs, ed2 = hD2[r] * rs;
            const float a = mus * mus, b = mud * mud;
            const float num1 = (a - b) * 0.5f + SSIM_C1;               // 2*mu1*mu2 + C1
            const float den1 = (a + b) * 0.5f + SSIM_C1;               // mu1^2+mu2^2 + C1
            const float num2 = (es2 - ed2 - (a - b)) * 0.5f + SSIM_C2; // 2*sigma12 + C2
            const float den2 = (es2 + ed2 - (a + b)) * 0.5f + SSIM_C2; // s1+s2 + C2
            lsum += (num1 * num2) * __builtin_amdgcn_rcpf(den1 * den2);
        }
    };

    // schedule: ring slot t%2; H(u) needs t=u and t=u+1 resident.
    do_V(0); do_V(1);
    do_H(0); do_V(2);
    do_H(1); do_V(3);
    do_H(2); do_V(4);
    do_H(3);

    // ---- per-wave reduction -> fp32 partial (no atomics, no cross-wave sync)
    #pragma unroll
    for (int off = 32; off > 0; off >>= 1)
        lsum += __shfl_down(lsum, off, 64);
    if (lane == 0) {
        const int bid = blockIdx.x + GXB * (blockIdx.y + GYB * blockIdx.z);
        partials[(bid << 2) | wv] = lsum;
    }
}

// 1 block x 1024 threads: 12 independent fp32 loads/thread, f64 accumulate.
__global__ __launch_bounds__(1024) void ssim_finalize_kernel(
    const float* __restrict__ partials, float* __restrict__ out)
{
    __shared__ double wred[16];
    const int tid  = threadIdx.x;
    const int lane = tid & 63;
    const int wv   = tid >> 6;
    double s = 0.0;
    #pragma unroll
    for (int i = 0; i < 12; ++i)               // 12*1024 == 12288 exactly
        s += (double)partials[tid + i * 1024];
    #pragma unroll
    for (int off = 32; off > 0; off >>= 1)
        s += __shfl_down(s, off, 64);
    if (lane == 0) wred[wv] = s;
    __syncthreads();
    if (wv == 0) {
        double v = (lane < 16) ? wred[lane] : 0.0;
        v += __shfl_down(v, 8, 64);
        v += __shfl_down(v, 4, 64);
        v += __shfl_down(v, 2, 64);
        v += __shfl_down(v, 1, 64);
        if (lane == 0) out[0] = (float)(v / (double)N_ELEM);
    }
}

extern "C" void kernel_launch(void* const* d_in, const int* in_sizes, int n_in,
                              void* d_out, int out_size, void* d_ws, size_t ws_size,
                              hipStream_t stream)
{
    const float* img1 = (const float*)d_in[0];
    const float* img2 = (const float*)d_in[1];
    float* partials   = (float*)d_ws;           // 12288 * 4B = 49 KB scratch
    float* out        = (float*)d_out;

    dim3 grid(GXB, GYB, NPLANES);
    ssim_tile_kernel<<<grid, dim3(256), 0, stream>>>(img1, img2, partials);
    ssim_finalize_kernel<<<1, dim3(1024), 0, stream>>>(partials, out);
}